// Round 2
// baseline (459.499 us; speedup 1.0000x reference)
//
#include <hip/hip_runtime.h>
#include <hip/hip_bf16.h>

// NATLayer fp32 I/O, bf16 internal compute. B=8, H=W=128, C=128, HEADS=4,
// d=32, KSIZE=7, N=16384 (1-D neighborhood over flattened N), M = B*N = 131072.
//
// Pipeline (14 dispatches, 2 row-chunks of 65536 for qkv/attn and MLP):
//  0. cvt_params: fp32 weights/biases -> bf16 param block   [ws 0 .. 0.5MB)
//  1. LN1(x fp32) -> xs bf16                                [ws +0.5MB, 33.5MB)
//  2x2. qkv chunk = xs @ qkv_w^T + b  -> qkvchunk bf16      [ws scratch region)
//  3x2. neighborhood attention -> attnout bf16              [d_out bytes 0..33.5MB)
//  4. x2 = x + attnout @ proj_w^T + b  (bf16)               [xs region, xs dead]
//  5. LN2(x2) -> ys bf16                                    [d_out bytes 33.5..67.1MB)
//  6x2. h = gelu(ys @ fc1_w^T + b) chunk -> hchunk bf16     [ws scratch region)
//  7x2. out = x2 + h @ fc2_w^T + b  -> fp32 d_out
// ws requirement: ~101 MB. d_out scratch ordering verified (fc2 chunk c writes
// fp32 rows of chunk c only, after fc1 chunk c has consumed its ys rows).

#define NPOS 16384
#define MROWS 131072
#define CHUNK 65536            // rows per chunk (multiple of NPOS)

typedef unsigned short ushort_t;
typedef __bf16 bf8 __attribute__((ext_vector_type(8)));
typedef float f4 __attribute__((ext_vector_type(4)));

// param block offsets (bf16 elems)
#define P_QKV_W 0
#define P_QKV_B 49152
#define P_PROJ_W 49536
#define P_PROJ_B 65920
#define P_FC1_W 66048
#define P_FC1_B 131584
#define P_FC2_W 132096
#define P_FC2_B 197632
#define P_TOTAL 197760

__device__ __forceinline__ float b2f(ushort_t u) {
    union { unsigned int i; float f; } v; v.i = ((unsigned int)u) << 16; return v.f;
}
__device__ __forceinline__ ushort_t f2b(float f) {
    __hip_bfloat16 h = __float2bfloat16(f);
    return *reinterpret_cast<ushort_t*>(&h);
}

// ---------------- fp32 -> bf16 weight conversion (one launch) ---------------
__global__ __launch_bounds__(256) void cvt_params(
    const float* __restrict__ qkv_w, const float* __restrict__ qkv_b,
    const float* __restrict__ proj_w, const float* __restrict__ proj_b,
    const float* __restrict__ fc1_w, const float* __restrict__ fc1_b,
    const float* __restrict__ fc2_w, const float* __restrict__ fc2_b,
    ushort_t* __restrict__ p)
{
    int i = blockIdx.x * 256 + threadIdx.x;
    if (i >= P_TOTAL) return;
    float v;
    if      (i < P_QKV_B)  v = qkv_w[i - P_QKV_W];
    else if (i < P_PROJ_W) v = qkv_b[i - P_QKV_B];
    else if (i < P_PROJ_B) v = proj_w[i - P_PROJ_W];
    else if (i < P_FC1_W)  v = proj_b[i - P_PROJ_B];
    else if (i < P_FC1_B)  v = fc1_w[i - P_FC1_W];
    else if (i < P_FC2_W)  v = fc1_b[i - P_FC1_B];
    else if (i < P_FC2_B)  v = fc2_w[i - P_FC2_W];
    else                   v = fc2_b[i - P_FC2_B];
    p[i] = f2b(v);
}

// ---------------- LayerNorm over C=128, one wave per row, out bf16 ----------
template<typename T>
__global__ __launch_bounds__(256) void ln_kernel(
    const T* __restrict__ x, const float* __restrict__ w,
    const float* __restrict__ b, ushort_t* __restrict__ out)
{
    int row  = blockIdx.x * 4 + (threadIdx.x >> 6);
    int lane = threadIdx.x & 63;
    int c0 = lane * 2;
    float v0, v1;
    if constexpr (sizeof(T) == 4) {
        float2 pv = *(const float2*)&x[(size_t)row * 128 + c0];
        v0 = pv.x; v1 = pv.y;
    } else {
        unsigned int pv = *(const unsigned int*)&x[(size_t)row * 128 + c0];
        v0 = b2f((ushort_t)(pv & 0xffff));
        v1 = b2f((ushort_t)(pv >> 16));
    }
    float s  = v0 + v1;
    float s2 = v0 * v0 + v1 * v1;
    #pragma unroll
    for (int off = 32; off; off >>= 1) {
        s  += __shfl_xor(s,  off, 64);
        s2 += __shfl_xor(s2, off, 64);
    }
    float mu   = s * (1.0f / 128.0f);
    float var  = s2 * (1.0f / 128.0f) - mu * mu;
    float rstd = rsqrtf(var + 1e-5f);
    float o0 = (v0 - mu) * rstd * w[c0]     + b[c0];
    float o1 = (v1 - mu) * rstd * w[c0 + 1] + b[c0 + 1];
    unsigned int pk = (unsigned int)f2b(o0) | ((unsigned int)f2b(o1) << 16);
    *(unsigned int*)&out[(size_t)row * 128 + c0] = pk;
}

// ---------------- NT GEMM: out[M,N] = A[M,K] @ Bw[N,K]^T + bias -------------
// 128x128 tile, BK=64, 4 waves each 64x64 via 4x4 of 16x16x32 bf16 MFMA.
// RESID: 0 none, 1 fp32 resid, 2 bf16 resid.  OUTF: fp32 output.
template<bool GELU, int RESID, bool OUTF>
__global__ __launch_bounds__(256, 2) void gemm_nt(
    const ushort_t* __restrict__ A, const ushort_t* __restrict__ Bw,
    const ushort_t* __restrict__ bias, const void* __restrict__ resid,
    void* __restrict__ out, int N, int Kdim)
{
    __shared__ ushort_t As[128][72];
    __shared__ ushort_t Bs[128][72];
    int m0 = blockIdx.x * 128, n0 = blockIdx.y * 128;
    int tid  = threadIdx.x;
    int wave = tid >> 6, lane = tid & 63;
    int wm = wave >> 1, wn = wave & 1;
    int quad = lane >> 4, lrow = lane & 15;

    f4 acc[4][4];
    #pragma unroll
    for (int i = 0; i < 4; i++)
        #pragma unroll
        for (int j = 0; j < 4; j++) {
            f4 z = {0.f, 0.f, 0.f, 0.f};
            acc[i][j] = z;
        }

    for (int k0 = 0; k0 < Kdim; k0 += 64) {
        #pragma unroll 4
        for (int i = tid; i < 1024; i += 256) {
            int r = i >> 3, c = (i & 7) << 3;
            *(uint4*)&As[r][c] = *(const uint4*)&A[(size_t)(m0 + r) * Kdim + k0 + c];
        }
        #pragma unroll 4
        for (int i = tid; i < 1024; i += 256) {
            int r = i >> 3, c = (i & 7) << 3;
            *(uint4*)&Bs[r][c] = *(const uint4*)&Bw[(size_t)(n0 + r) * Kdim + k0 + c];
        }
        __syncthreads();
        #pragma unroll
        for (int ks = 0; ks < 64; ks += 32) {
            bf8 av[4], bv[4];
            #pragma unroll
            for (int i = 0; i < 4; i++)
                av[i] = *(const bf8*)&As[wm * 64 + i * 16 + lrow][ks + quad * 8];
            #pragma unroll
            for (int j = 0; j < 4; j++)
                bv[j] = *(const bf8*)&Bs[wn * 64 + j * 16 + lrow][ks + quad * 8];
            #pragma unroll
            for (int i = 0; i < 4; i++)
                #pragma unroll
                for (int j = 0; j < 4; j++)
                    acc[i][j] = __builtin_amdgcn_mfma_f32_16x16x32_bf16(
                        av[i], bv[j], acc[i][j], 0, 0, 0);
        }
        __syncthreads();
    }

    float bs[4];
    #pragma unroll
    for (int j = 0; j < 4; j++) bs[j] = b2f(bias[n0 + wn * 64 + j * 16 + lrow]);

    #pragma unroll
    for (int i = 0; i < 4; i++) {
        #pragma unroll
        for (int r = 0; r < 4; r++) {
            int grow = m0 + wm * 64 + i * 16 + quad * 4 + r;
            #pragma unroll
            for (int j = 0; j < 4; j++) {
                int gcol = n0 + wn * 64 + j * 16 + lrow;
                float v = acc[i][j][r] + bs[j];
                if (GELU) v = 0.5f * v * (1.0f + erff(v * 0.70710678118654752f));
                if (RESID == 1) v += ((const float*)resid)[(size_t)grow * N + gcol];
                if (RESID == 2) v += b2f(((const ushort_t*)resid)[(size_t)grow * N + gcol]);
                if (OUTF) ((float*)out)[(size_t)grow * N + gcol] = v;
                else      ((ushort_t*)out)[(size_t)grow * N + gcol] = f2b(v);
            }
        }
    }
}

// ---------------- Neighborhood attention (k=7, 1-D over N=16384) ------------
// 128 threads per token; head = c>>5; 32-lane shuffle dot-reduce. bf16 in/out.
__global__ __launch_bounds__(256) void nat_attn(
    const ushort_t* __restrict__ qkv, const float* __restrict__ rpb,
    ushort_t* __restrict__ out)
{
    int t     = blockIdx.x * 2 + (threadIdx.x >> 7);   // row within chunk
    int local = threadIdx.x & 127;
    int n     = t & (NPOS - 1);
    int h     = local >> 5;

    float q = b2f(qkv[(size_t)t * 384 + local]) * 0.17677669529663687f; // d^-0.5
    int start = n - 3;
    if (start < 0) start = 0;
    if (start > NPOS - 7) start = NPOS - 7;

    const ushort_t* base = qkv + (size_t)(t - n + start) * 384;
    float logit[7], vv[7];
    #pragma unroll
    for (int j = 0; j < 7; j++) {
        float kv = b2f(base[j * 384 + 128 + local]);
        float p  = q * kv;
        p += __shfl_xor(p, 16, 32);
        p += __shfl_xor(p,  8, 32);
        p += __shfl_xor(p,  4, 32);
        p += __shfl_xor(p,  2, 32);
        p += __shfl_xor(p,  1, 32);
        int bidx = start + j - n + 6;           // in [0,12]
        logit[j] = p + rpb[h * 13 + bidx];
        vv[j]    = b2f(base[j * 384 + 256 + local]);
    }
    float m = logit[0];
    #pragma unroll
    for (int j = 1; j < 7; j++) m = fmaxf(m, logit[j]);
    float s = 0.f, o = 0.f;
    #pragma unroll
    for (int j = 0; j < 7; j++) {
        float e = __expf(logit[j] - m);
        s += e;
        o += e * vv[j];
    }
    out[(size_t)t * 128 + local] = f2b(o / s);
}

extern "C" void kernel_launch(void* const* d_in, const int* in_sizes, int n_in,
                              void* d_out, int out_size, void* d_ws, size_t ws_size,
                              hipStream_t stream) {
    const float* x      = (const float*)d_in[0];
    const float* n1w    = (const float*)d_in[1];
    const float* n1b    = (const float*)d_in[2];
    const float* qkv_w  = (const float*)d_in[3];
    const float* qkv_b  = (const float*)d_in[4];
    const float* rpb    = (const float*)d_in[5];
    const float* proj_w = (const float*)d_in[6];
    const float* proj_b = (const float*)d_in[7];
    const float* n2w    = (const float*)d_in[8];
    const float* n2b    = (const float*)d_in[9];
    const float* fc1_w  = (const float*)d_in[10];
    const float* fc1_b  = (const float*)d_in[11];
    const float* fc2_w  = (const float*)d_in[12];
    const float* fc2_b  = (const float*)d_in[13];

    ushort_t* ws      = (ushort_t*)d_ws;
    ushort_t* params  = ws;                     // 197,760 elems (pad to 262144)
    ushort_t* xs      = ws + 262144;            // 16,777,216 elems (also x2)
    ushort_t* x2      = xs;
    ushort_t* scratch = ws + 17039360;          // qkvchunk (25.2M) / hchunk (33.5M)
    // d_out (fp32, 67.1MB) doubles as bf16 scratch:
    ushort_t* attnout = (ushort_t*)d_out;               // bytes [0, 33.5MB)
    ushort_t* ys      = attnout + 16777216;             // bytes [33.5, 67.1MB)
    float*    outf    = (float*)d_out;

    const size_t RC = (size_t)CHUNK * 128;      // activation elems per chunk

    cvt_params<<<(P_TOTAL + 255) / 256, 256, 0, stream>>>(
        qkv_w, qkv_b, proj_w, proj_b, fc1_w, fc1_b, fc2_w, fc2_b, params);

    ln_kernel<float><<<MROWS / 4, 256, 0, stream>>>(x, n1w, n1b, xs);

    for (int c = 0; c < 2; c++) {
        gemm_nt<false, 0, false><<<dim3(CHUNK / 128, 3), 256, 0, stream>>>(
            xs + c * RC, params + P_QKV_W, params + P_QKV_B, nullptr,
            scratch, 384, 128);
        nat_attn<<<CHUNK / 2, 256, 0, stream>>>(scratch, rpb, attnout + c * RC);
    }

    gemm_nt<false, 1, false><<<dim3(MROWS / 128, 1), 256, 0, stream>>>(
        attnout, params + P_PROJ_W, params + P_PROJ_B, x, x2, 128, 128);

    ln_kernel<ushort_t><<<MROWS / 4, 256, 0, stream>>>(x2, n2w, n2b, ys);

    for (int c = 0; c < 2; c++) {
        gemm_nt<true, 0, false><<<dim3(CHUNK / 128, 4), 256, 0, stream>>>(
            ys + c * RC, params + P_FC1_W, params + P_FC1_B, nullptr,
            scratch, 512, 128);
        gemm_nt<false, 2, true><<<dim3(CHUNK / 128, 1), 256, 0, stream>>>(
            scratch, params + P_FC2_W, params + P_FC2_B, x2 + c * RC,
            outf + c * RC, 128, 512);
    }
}